// Round 19
// baseline (604.363 us; speedup 1.0000x reference)
//
#include <hip/hip_runtime.h>
#include <math.h>

// B=4, N=1024, C=768, H=12, D=64
// ws: q[12.58MB] k qpk kpk vpk qgrh kgrh qn4 kn4  (= 75,890,688 B base)
// BASE region reused serially: {xpk,wpk} -> {Vpk2,Wg,taug,Gpart} -> Sbuf(per-batch).
// ppk lives in k region (k f32 dead after qr_fact). attno_pk aliases q region.

typedef __attribute__((ext_vector_type(8))) short short8;
typedef __attribute__((ext_vector_type(4))) float f32x4;

__device__ __forceinline__ unsigned bf16r(float x) {
    unsigned u = __float_as_uint(x);
    return (u + 0x7FFFu + ((u >> 16) & 1u)) >> 16;
}
__device__ __forceinline__ unsigned packhl(float x) {
    unsigned u = __float_as_uint(x);
    unsigned hi = (u + 0x7FFFu + ((u >> 16) & 1u)) & 0xFFFF0000u;
    float lo = x - __uint_as_float(hi);
    unsigned ul = __float_as_uint(lo);
    unsigned l16 = (ul + 0x7FFFu + ((ul >> 16) & 1u)) >> 16;
    return hi | (l16 & 0xFFFFu);
}
__device__ __forceinline__ float unpackhl(unsigned u) {
    return __uint_as_float(u & 0xFFFF0000u) + __uint_as_float(u << 16);
}
union U4S8 { uint4 u; short8 s; };
__device__ __forceinline__ short8 mk_hi(uint4 a, uint4 b) {
    U4S8 r;
    r.u.x = __builtin_amdgcn_perm(a.y, a.x, 0x07060302);
    r.u.y = __builtin_amdgcn_perm(a.w, a.z, 0x07060302);
    r.u.z = __builtin_amdgcn_perm(b.y, b.x, 0x07060302);
    r.u.w = __builtin_amdgcn_perm(b.w, b.z, 0x07060302);
    return r.s;
}
__device__ __forceinline__ short8 mk_lo(uint4 a, uint4 b) {
    U4S8 r;
    r.u.x = __builtin_amdgcn_perm(a.y, a.x, 0x05040100);
    r.u.y = __builtin_amdgcn_perm(a.w, a.z, 0x05040100);
    r.u.z = __builtin_amdgcn_perm(b.y, b.x, 0x05040100);
    r.u.w = __builtin_amdgcn_perm(b.w, b.z, 0x05040100);
    return r.s;
}
__device__ __forceinline__ uint4 ld4v(const unsigned* vp, int mbase, int d) {
    uint4 r;
    r.x = vp[(size_t)(mbase + 0) * 64 + d];
    r.y = vp[(size_t)(mbase + 1) * 64 + d];
    r.z = vp[(size_t)(mbase + 2) * 64 + d];
    r.w = vp[(size_t)(mbase + 3) * 64 + d];
    return r;
}
#define MFMA(a,b,c) __builtin_amdgcn_mfma_f32_16x16x32_bf16(a, b, c, 0, 0, 0)

// ---------------- pack: f32 -> hi|lo packed u32 ----------------
__global__ __launch_bounds__(256) void pack_f32(
    const float* __restrict__ src, unsigned* __restrict__ dst, int n4)
{
    int i = blockIdx.x * 256 + threadIdx.x;
    if (i < n4) {
        float4 v = *(const float4*)&src[(size_t)i * 4];
        uint4 o;
        o.x = packhl(v.x); o.y = packhl(v.y); o.z = packhl(v.z); o.w = packhl(v.w);
        *(uint4*)&dst[(size_t)i * 4] = o;
    }
}

// ---------------- K1-MFMA: qkv = x @ w^T + b (32x64 tile) ----------------
__global__ __launch_bounds__(256) void qkv_mfma(
    const unsigned* __restrict__ xpk, const unsigned* __restrict__ wpk,
    const float* __restrict__ bias,
    float* __restrict__ q, float* __restrict__ k,
    unsigned* __restrict__ qpk, unsigned* __restrict__ kpk, unsigned* __restrict__ vpk)
{
    __shared__ unsigned xT[32 * 64];
    __shared__ unsigned wT[64 * 64];
    const int tid = threadIdx.x;
    const int lane = tid & 63;
    const int w = tid >> 6;
    const int rowL = lane & 15;
    const int g = lane >> 4;
    const int r7 = rowL & 7;
    const int n0 = blockIdx.x * 64;
    const int m0 = blockIdx.y * 32;
    f32x4 accA = {0,0,0,0}, accB = {0,0,0,0};

    for (int kk0 = 0; kk0 < 768; kk0 += 64) {
        __syncthreads();
#pragma unroll
        for (int e = 0; e < 2; e++) {
            int ci = tid + 256 * e; int R = ci >> 4, c = ci & 15;
            uint4 v = *(const uint4*)&xpk[(size_t)(m0 + R) * 768 + kk0 + c * 4];
            *(uint4*)&xT[R * 64 + ((c ^ (R & 7)) << 2)] = v;
        }
#pragma unroll
        for (int e = 0; e < 4; e++) {
            int ci = tid + 256 * e; int R = ci >> 4, c = ci & 15;
            uint4 v = *(const uint4*)&wpk[(size_t)(n0 + R) * 768 + kk0 + c * 4];
            *(uint4*)&wT[R * 64 + ((c ^ (R & 7)) << 2)] = v;
        }
        __syncthreads();
#pragma unroll
        for (int ks = 0; ks < 2; ks++) {
            int c0 = ks * 8 + g * 2;
            uint4 b0 = *(const uint4*)&wT[(w * 16 + rowL) * 64 + ((c0 ^ r7) << 2)];
            uint4 b1 = *(const uint4*)&wT[(w * 16 + rowL) * 64 + (((c0 + 1) ^ r7) << 2)];
            short8 whi = mk_hi(b0, b1), wlo = mk_lo(b0, b1);
            uint4 a0 = *(const uint4*)&xT[rowL * 64 + ((c0 ^ r7) << 2)];
            uint4 a1 = *(const uint4*)&xT[rowL * 64 + (((c0 + 1) ^ r7) << 2)];
            short8 xhi = mk_hi(a0, a1), xlo = mk_lo(a0, a1);
            accA = MFMA(xhi, whi, accA);
            accA = MFMA(xhi, wlo, accA);
            accA = MFMA(xlo, whi, accA);
            uint4 a2 = *(const uint4*)&xT[(16 + rowL) * 64 + ((c0 ^ r7) << 2)];
            uint4 a3 = *(const uint4*)&xT[(16 + rowL) * 64 + (((c0 + 1) ^ r7) << 2)];
            short8 xhi2 = mk_hi(a2, a3), xlo2 = mk_lo(a2, a3);
            accB = MFMA(xhi2, whi, accB);
            accB = MFMA(xhi2, wlo, accB);
            accB = MFMA(xlo2, whi, accB);
        }
    }
    const int col = n0 + w * 16 + rowL;
    const float bv = bias[col];
    const int s = (n0 >= 1536) ? 2 : ((n0 >= 768) ? 1 : 0);
    const int hc = col - s * 768;
    const int head = hc >> 6;
    const int cin = hc & 63;
#pragma unroll
    for (int half = 0; half < 2; half++) {
        f32x4 acc = half ? accB : accA;
#pragma unroll
        for (int r = 0; r < 4; r++) {
            int row = m0 + half * 16 + g * 4 + r;
            int bb = row >> 10, n = row & 1023;
            size_t idx = ((size_t)(bb * 12 + head) << 16) + ((size_t)n << 6) + cin;
            float val = acc[r] + bv;
            if (s == 0)      { q[idx] = val; qpk[idx] = packhl(val); }
            else if (s == 1) { k[idx] = val; kpk[idx] = packhl(val); }
            else             { vpk[idx] = packhl(val); }
        }
    }
}

// ---------------- K4-MFMA: out = attno_pk @ ppk^T + proj_b ----------------
__global__ __launch_bounds__(256) void proj_mfma(
    const unsigned* __restrict__ apk, const unsigned* __restrict__ wpk,
    const float* __restrict__ bias, float* __restrict__ out)
{
    __shared__ unsigned xT[32 * 64];
    __shared__ unsigned wT[64 * 64];
    const int tid = threadIdx.x;
    const int lane = tid & 63;
    const int w = tid >> 6;
    const int rowL = lane & 15;
    const int g = lane >> 4;
    const int r7 = rowL & 7;
    const int n0 = blockIdx.x * 64;
    const int m0 = blockIdx.y * 32;
    f32x4 accA = {0,0,0,0}, accB = {0,0,0,0};

    for (int kk0 = 0; kk0 < 768; kk0 += 64) {
        __syncthreads();
#pragma unroll
        for (int e = 0; e < 2; e++) {
            int ci = tid + 256 * e; int R = ci >> 4, c = ci & 15;
            uint4 v = *(const uint4*)&apk[(size_t)(m0 + R) * 768 + kk0 + c * 4];
            *(uint4*)&xT[R * 64 + ((c ^ (R & 7)) << 2)] = v;
        }
#pragma unroll
        for (int e = 0; e < 4; e++) {
            int ci = tid + 256 * e; int R = ci >> 4, c = ci & 15;
            uint4 v = *(const uint4*)&wpk[(size_t)(n0 + R) * 768 + kk0 + c * 4];
            *(uint4*)&wT[R * 64 + ((c ^ (R & 7)) << 2)] = v;
        }
        __syncthreads();
#pragma unroll
        for (int ks = 0; ks < 2; ks++) {
            int c0 = ks * 8 + g * 2;
            uint4 b0 = *(const uint4*)&wT[(w * 16 + rowL) * 64 + ((c0 ^ r7) << 2)];
            uint4 b1 = *(const uint4*)&wT[(w * 16 + rowL) * 64 + (((c0 + 1) ^ r7) << 2)];
            short8 whi = mk_hi(b0, b1), wlo = mk_lo(b0, b1);
            uint4 a0 = *(const uint4*)&xT[rowL * 64 + ((c0 ^ r7) << 2)];
            uint4 a1 = *(const uint4*)&xT[rowL * 64 + (((c0 + 1) ^ r7) << 2)];
            short8 xhi = mk_hi(a0, a1), xlo = mk_lo(a0, a1);
            accA = MFMA(xhi, whi, accA);
            accA = MFMA(xhi, wlo, accA);
            accA = MFMA(xlo, whi, accA);
            uint4 a2 = *(const uint4*)&xT[(16 + rowL) * 64 + ((c0 ^ r7) << 2)];
            uint4 a3 = *(const uint4*)&xT[(16 + rowL) * 64 + (((c0 + 1) ^ r7) << 2)];
            short8 xhi2 = mk_hi(a2, a3), xlo2 = mk_lo(a2, a3);
            accB = MFMA(xhi2, whi, accB);
            accB = MFMA(xhi2, wlo, accB);
            accB = MFMA(xlo2, whi, accB);
        }
    }
    const int col = n0 + w * 16 + rowL;
    const float bv = bias[col];
#pragma unroll
    for (int half = 0; half < 2; half++) {
        f32x4 acc = half ? accB : accA;
#pragma unroll
        for (int r = 0; r < 4; r++) {
            int row = m0 + half * 16 + g * 4 + r;
            out[(size_t)row * 768 + col] = acc[r] + bv;
        }
    }
}

// ---------------- K1b: squared row norms ----------------
__global__ __launch_bounds__(256) void row_norms(
    const float* __restrict__ q, const float* __restrict__ k,
    float* __restrict__ qn4, float* __restrict__ kn4)
{
    int wid = blockIdx.x * 4 + (threadIdx.x >> 6);
    int lane = threadIdx.x & 63;
    const float* src; float* dst; int r;
    if (wid < 49152) { src = q; dst = qn4; r = wid; }
    else             { src = k; dst = kn4; r = wid - 49152; }
    float xv = src[(size_t)r * 64 + lane];
    float s = xv * xv;
#pragma unroll
    for (int m = 1; m < 64; m <<= 1) s += __shfl_xor(s, m, 64);
    if (lane == 0) dst[r] = s * s;
}

// ---------------- K2a: Householder factorization (LAPACK signs) ----------------
__global__ __launch_bounds__(1024)
__attribute__((amdgpu_waves_per_eu(4, 4)))
void qr_fact(const float* __restrict__ q, const float* __restrict__ k,
             unsigned* __restrict__ Vp_, float* __restrict__ taug)
{
    const int id = blockIdx.x;
    const float* src = (id & 1) ? k : q;
    src += (size_t)(id >> 1) << 16;
    unsigned* Vp = Vp_ + (size_t)id * 65536;
    const int tid = threadIdx.x;
    const int lane = tid & 63;
    const int w = tid >> 6;
    __shared__ float vbufA[1024];
    __shared__ float vbufB[1024];
    __shared__ float taub[64];

    float a[4][16];
#pragma unroll
    for (int c = 0; c < 4; c++)
#pragma unroll
        for (int i = 0; i < 16; i++)
            a[c][i] = src[(i * 64 + lane) * 64 + 4 * w + c];

    if (w == 0) {
        float part = 0.f;
#pragma unroll
        for (int i = 0; i < 16; i++) part += a[0][i] * a[0][i];
#pragma unroll
        for (int m = 1; m < 64; m <<= 1) part += __shfl_xor(part, m, 64);
        float sigma = part;
        float xd = __shfl(a[0][0], 0, 64);
        float nrm = sqrtf(sigma);
        float beta = (xd >= 0.f) ? -nrm : nrm;
        float vd = xd - beta;
        float vtv = (sigma - xd * xd) + vd * vd;
        float tau2 = (vtv > 0.f) ? 2.f / vtv : 0.f;
        if (lane == 0) a[0][0] = vd;
#pragma unroll
        for (int i = 0; i < 16; i++) vbufA[i * 64 + lane] = a[0][i];
        if (lane == 0) taub[0] = tau2;
    }
    __syncthreads();

    for (int d = 0; d < 64; d++) {
        const int jb = 4 * w;
        if (jb + 3 > d) {
            float* vb = (d & 1) ? vbufB : vbufA;
            float vr[16];
#pragma unroll
            for (int i = 0; i < 16; i++) vr[i] = vb[i * 64 + lane];
            float t2 = taub[d];
            float dp0 = 0.f, dp1 = 0.f, dp2 = 0.f, dp3 = 0.f;
#pragma unroll
            for (int i = 0; i < 16; i++) {
                dp0 += vr[i] * a[0][i];
                dp1 += vr[i] * a[1][i];
                dp2 += vr[i] * a[2][i];
                dp3 += vr[i] * a[3][i];
            }
#pragma unroll
            for (int m = 1; m < 64; m <<= 1) {
                dp0 += __shfl_xor(dp0, m, 64);
                dp1 += __shfl_xor(dp1, m, 64);
                dp2 += __shfl_xor(dp2, m, 64);
                dp3 += __shfl_xor(dp3, m, 64);
            }
            float s0 = t2 * dp0, s1 = t2 * dp1, s2 = t2 * dp2, s3 = t2 * dp3;
            if (jb + 0 > d) {
#pragma unroll
                for (int i = 0; i < 16; i++) a[0][i] -= s0 * vr[i];
            }
            if (jb + 1 > d) {
#pragma unroll
                for (int i = 0; i < 16; i++) a[1][i] -= s1 * vr[i];
            }
            if (jb + 2 > d) {
#pragma unroll
                for (int i = 0; i < 16; i++) a[2][i] -= s2 * vr[i];
            }
            {
#pragma unroll
                for (int i = 0; i < 16; i++) a[3][i] -= s3 * vr[i];
            }
        }
        if (d < 63) {
            const int dn = d + 1;
            if (w == (dn >> 2)) {
                const int cd = dn & 3;
#pragma unroll
                for (int c = 0; c < 4; c++) if (c == cd) {
                    float part = 0.f;
#pragma unroll
                    for (int i = 0; i < 16; i++) {
                        int r = i * 64 + lane;
                        float xx = a[c][i];
                        part += (r >= dn) ? xx * xx : 0.f;
                    }
#pragma unroll
                    for (int m = 1; m < 64; m <<= 1) part += __shfl_xor(part, m, 64);
                    float sigma = part;
                    float xd = __shfl(a[c][0], dn, 64);
                    float nrm = sqrtf(sigma);
                    float beta = (xd >= 0.f) ? -nrm : nrm;
                    float vd = xd - beta;
                    float vtv = (sigma - xd * xd) + vd * vd;
                    float tau2 = (vtv > 0.f) ? 2.f / vtv : 0.f;
                    if (lane == dn) a[c][0] = vd;
                    float* vbn = (dn & 1) ? vbufB : vbufA;
#pragma unroll
                    for (int i = 0; i < 16; i++) {
                        int r = i * 64 + lane;
                        vbn[i * 64 + lane] = (r < dn) ? 0.f : a[c][i];
                    }
                    if (lane == 0) taub[dn] = tau2;
                }
            }
        }
        __syncthreads();
    }

    if (tid < 64) taug[id * 64 + tid] = taub[tid];
#pragma unroll
    for (int c = 0; c < 4; c++) {
        int j = 4 * w + c;
#pragma unroll
        for (int i = 0; i < 16; i++) {
            int r = i * 64 + lane;
            float vv = (r < j) ? 0.f : a[c][i];
            Vp[(size_t)j * 1024 + r] = packhl(vv);
        }
    }
}

// ---------------- K2b-1: partial G = V^T V over 256-row slab (MFMA) ----------------
__global__ __launch_bounds__(256) void qr_gpart(
    const unsigned* __restrict__ Vp_, float* __restrict__ Gpart)
{
    const int id = blockIdx.x;
    const int sl = blockIdx.y;
    const unsigned* Vp = Vp_ + (size_t)id * 65536;
    __shared__ unsigned Vc[64 * 32];
    const int tid = threadIdx.x;
    const int lane = tid & 63;
    const int w = tid >> 6;
    const int rowL = lane & 15;
    const int g = lane >> 4;

    f32x4 acc0 = {0,0,0,0}, acc1 = {0,0,0,0}, acc2 = {0,0,0,0}, acc3 = {0,0,0,0};
    for (int r0 = sl * 256; r0 < sl * 256 + 256; r0 += 32) {
        __syncthreads();
#pragma unroll
        for (int e = 0; e < 2; e++) {
            int ci = tid + 256 * e;
            int row = ci >> 3, c = ci & 7;
            uint4 v = *(const uint4*)&Vp[(size_t)row * 1024 + r0 + c * 4];
            *(uint4*)&Vc[row * 32 + ((c ^ (row & 7)) << 2)] = v;
        }
        __syncthreads();
        int ra = w * 16 + rowL;
        uint4 a0 = *(const uint4*)&Vc[ra * 32 + (((g * 2) ^ (ra & 7)) << 2)];
        uint4 a1 = *(const uint4*)&Vc[ra * 32 + (((g * 2 + 1) ^ (ra & 7)) << 2)];
        short8 Ahi = mk_hi(a0, a1), Alo = mk_lo(a0, a1);
#define GDO(jt, accv) { int rb = jt * 16 + rowL; \
        uint4 b0 = *(const uint4*)&Vc[rb * 32 + (((g * 2) ^ (rb & 7)) << 2)]; \
        uint4 b1 = *(const uint4*)&Vc[rb * 32 + (((g * 2 + 1) ^ (rb & 7)) << 2)]; \
        short8 Bhi = mk_hi(b0, b1), Blo = mk_lo(b0, b1); \
        accv = MFMA(Ahi, Bhi, accv); accv = MFMA(Ahi, Blo, accv); accv = MFMA(Alo, Bhi, accv); }
        GDO(0, acc0) GDO(1, acc1) GDO(2, acc2) GDO(3, acc3)
#undef GDO
    }
    float* dst = Gpart + ((size_t)(id * 4 + sl) << 12);
#define GWR(jt, accv) { \
    dst[(w * 16 + g * 4 + 0) * 64 + jt * 16 + rowL] = accv[0]; \
    dst[(w * 16 + g * 4 + 1) * 64 + jt * 16 + rowL] = accv[1]; \
    dst[(w * 16 + g * 4 + 2) * 64 + jt * 16 + rowL] = accv[2]; \
    dst[(w * 16 + g * 4 + 3) * 64 + jt * 16 + rowL] = accv[3]; }
    GWR(0, acc0) GWR(1, acc1) GWR(2, acc2) GWR(3, acc3)
#undef GWR
}

// ---------------- K2b-2: W via back-substitution ----------------
__global__ __launch_bounds__(256) void qr_tw2(
    const unsigned* __restrict__ Vp_, const float* __restrict__ taug,
    const float* __restrict__ Gpart, float* __restrict__ Wg)
{
    const int id = blockIdx.x;
    const unsigned* Vp = Vp_ + (size_t)id * 65536;
    __shared__ float G_s[64 * 65];
    __shared__ float wbuf[64];
    __shared__ float tau_s[64];
    const int tid = threadIdx.x;
    if (tid < 64) tau_s[tid] = taug[id * 64 + tid];
    const float* Gp = Gpart + ((size_t)(id * 4) << 12);
#pragma unroll
    for (int e = 0; e < 16; e++) {
        int idx = tid + 256 * e;
        float sum = Gp[idx] + Gp[4096 + idx] + Gp[8192 + idx] + Gp[12288 + idx];
        G_s[(idx >> 6) * 65 + (idx & 63)] = sum;
    }
    const int i = tid >> 2;
    const int cq = tid & 3;
    float regA[16];
#pragma unroll
    for (int cc = 0; cc < 16; cc++)
        regA[cc] = unpackhl(Vp[(size_t)i * 1024 + cq * 16 + cc]);
    __syncthreads();
    for (int j = 63; j >= 0; j--) {
        if (i == j) {
            float tj = tau_s[j];
#pragma unroll
            for (int cc = 0; cc < 16; cc++) {
                regA[cc] *= tj;
                wbuf[cq * 16 + cc] = regA[cc];
            }
        }
        __syncthreads();
        if (i < j) {
            float gij = G_s[i * 65 + j];
#pragma unroll
            for (int cc = 0; cc < 16; cc++)
                regA[cc] = fmaf(-gij, wbuf[cq * 16 + cc], regA[cc]);
        }
        __syncthreads();
    }
#pragma unroll
    for (int cc = 0; cc < 16; cc++)
        Wg[(size_t)id * 4096 + i * 64 + cq * 16 + cc] = regA[cc];
}

// ---------------- K2c: Q = [I;0] - V W, bf16 output ----------------
__global__ __launch_bounds__(256) void qr_formq(
    const unsigned* __restrict__ Vp_, const float* __restrict__ Wg,
    unsigned short* __restrict__ qgrh, unsigned short* __restrict__ kgrh)
{
    const int id = blockIdx.x;
    const int rb = blockIdx.y;
    const unsigned* Vp = Vp_ + (size_t)id * 65536;
    const float* Wm = Wg + (size_t)id * 4096;
    unsigned short* dst = ((id & 1) ? kgrh : qgrh) + ((size_t)(id >> 1) << 16);
    __shared__ float Vl[64 * 65];
    __shared__ float Wl[64 * 64];
    const int tid = threadIdx.x;
    const int rbase = rb * 64;
#pragma unroll
    for (int e = 0; e < 16; e++) {
        int idx = tid + 256 * e;
        int j = idx >> 6, rl = idx & 63;
        Vl[rl * 65 + j] = unpackhl(Vp[(size_t)j * 1024 + rbase + rl]);
        Wl[idx] = Wm[idx];
    }
    __syncthreads();
    const int rl = tid >> 2;
    const int cg = (tid & 3) << 4;
    const int rglob = rbase + rl;
    unsigned short outv[16];
#pragma unroll
    for (int cc = 0; cc < 16; cc++) {
        int c = cg + cc;
        float s = (rglob == c) ? 1.f : 0.f;
        for (int j = 0; j < 64; j++) s -= Vl[rl * 65 + j] * Wl[j * 64 + c];
        outv[cc] = (unsigned short)bf16r(s);
    }
#pragma unroll
    for (int cc = 0; cc < 16; cc += 4)
        *(ushort4*)&dst[(size_t)rglob * 64 + cg + cc] = *(ushort4*)&outv[cc];
}

// ================= SPLIT ATTENTION PATH =================
// scores: 512 thr / 8 waves; wave = (n-group 0/1) x (m-quad 0-3), 32-row n-tile.
#define SC_EACH12(F) F(0) F(1) F(2) F(3) F(4) F(5) F(6) F(7) F(8) F(9) F(10) F(11)
#define SC_DECLY(o) float y##o##_0 = 0.f, y##o##_1 = 0.f, y##o##_2 = 0.f, y##o##_3 = 0.f;
#define SC_LOADC(o) const float cA##o = cw[o * 36 + h], \
                                cB##o = cw[o * 36 + 12 + h], \
                                cC##o = cw[o * 36 + 24 + h];
#define SC_CONV1(o,r) y##o##_##r = fmaf(cA##o, att, fmaf(cB##o, rie, fmaf(cC##o, gra, y##o##_##r)));
#define SC_CONVROW(r) SC_CONV1(0,r) SC_CONV1(1,r) SC_CONV1(2,r) SC_CONV1(3,r) SC_CONV1(4,r) SC_CONV1(5,r) \
                      SC_CONV1(6,r) SC_CONV1(7,r) SC_CONV1(8,r) SC_CONV1(9,r) SC_CONV1(10,r) SC_CONV1(11,r)
#define SC_SCORE(r) { \
    float qk = s1[r], gr = s2[r]; \
    float qn4v = qn4s[ng * 16 + g * 4 + r]; \
    float att = qk * scale; \
    float d2 = qn4v + kn4v - 2.f * qk * qk; \
    float rie = -sqrtf(fmaxf(d2, 0.f) + 1e-8f) * riem_scale; \
    float gra = gr * gr * grass_scale; \
    SC_CONVROW(r) }
#define SC_OUT(o) { \
    float inv = bn_gamma[o] * rsqrtf(bn_var[o] + 1e-5f); \
    float Bb = fmaf(conv_b[o] - bn_mean[o], inv, bn_beta[o]); \
    float* dst = Sbuf + ((size_t)(z * 12 + o) * 1024 + n0 + ng * 16) * 1024 + m0 + mq * 16 + rowL; \
    dst[(size_t)(g * 4 + 0) * 1024] = fmaf(y##o##_0, inv, Bb); \
    dst[(size_t)(g * 4 + 1) * 1024] = fmaf(y##o##_1, inv, Bb); \
    dst[(size_t)(g * 4 + 2) * 1024] = fmaf(y##o##_2, inv, Bb); \
    dst[(size_t)(g * 4 + 3) * 1024] = fmaf(y##o##_3, inv, Bb); }

__global__ __launch_bounds__(512) void sattn_scores(
    const unsigned* __restrict__ qpk, const unsigned* __restrict__ kpk,
    const unsigned short* __restrict__ qgrh, const unsigned short* __restrict__ kgrh,
    const float* __restrict__ qn4g, const float* __restrict__ kn4g,
    const float* __restrict__ cw, const float* __restrict__ conv_b,
    const float* __restrict__ bn_gamma, const float* __restrict__ bn_beta,
    const float* __restrict__ bn_mean, const float* __restrict__ bn_var,
    const float* __restrict__ scale_p, const float* __restrict__ riem_p,
    const float* __restrict__ grass_p, float* __restrict__ Sbuf, int b0)
{
    __shared__ unsigned qT[32 * 64];
    __shared__ unsigned short qgT[32 * 64];
    __shared__ unsigned kL[64 * 64];
    __shared__ unsigned short kgrL[64 * 64];
    __shared__ float qn4s[32];
    __shared__ float kn4s[64];

    const int tid = threadIdx.x;
    const int lane = tid & 63;
    const int w8 = tid >> 6;
    const int mq = w8 & 3;
    const int ng = w8 >> 2;
    const int rowL = lane & 15;
    const int g = lane >> 4;
    const int r7 = rowL & 7;
    const int m0 = blockIdx.x * 64;
    const int n0 = blockIdx.y * 32;
    const int z = blockIdx.z;
    const int b = b0 + z;
    const float scale = scale_p[0], riem_scale = riem_p[0], grass_scale = grass_p[0];

    SC_EACH12(SC_DECLY)

    for (int h = 0; h < 12; h++) {
        __syncthreads();
        {
            int R = tid >> 4, c = tid & 15;
            uint4 v = *(const uint4*)&qpk[((size_t)(b * 12 + h) << 16) + (size_t)(n0 + R) * 64 + c * 4];
            *(uint4*)&qT[R * 64 + ((c ^ (R & 7)) << 2)] = v;
        }
        if (tid < 256) {
            int R = tid >> 3, c = tid & 7;
            uint4 v = *(const uint4*)&qgrh[((size_t)(b * 12 + h) << 16) + (size_t)(n0 + R) * 64 + c * 8];
            *(uint4*)&qgT[R * 64 + ((c ^ (R & 7)) << 3)] = v;
        }
#pragma unroll
        for (int e = 0; e < 2; e++) {
            int ci = tid + 512 * e; int m = ci >> 4, c = ci & 15;
            uint4 v = *(const uint4*)&kpk[((size_t)(b * 12 + h) << 16) + (size_t)(m0 + m) * 64 + c * 4];
            *(uint4*)&kL[m * 64 + ((c ^ (m & 7)) << 2)] = v;
        }
        {
            int ci = tid; int m = ci >> 3, c = ci & 7;
            uint4 v = *(const uint4*)&kgrh[((size_t)(b * 12 + h) << 16) + (size_t)(m0 + m) * 64 + c * 8];
            *(uint4*)&kgrL[m * 64 + ((c ^ (m & 7)) << 3)] = v;
        }
        if (tid < 64) kn4s[tid] = kn4g[(size_t)(b * 12 + h) * 1024 + m0 + tid];
        if (tid < 32) qn4s[tid] = qn4g[(size_t)(b * 12 + h) * 1024 + n0 + tid];
        __syncthreads();

        float kn4v = kn4s[mq * 16 + rowL];
        f32x4 s1 = {0,0,0,0}, s2 = {0,0,0,0};
#pragma unroll
        for (int ks = 0; ks < 2; ks++) {
            int c0 = ks * 8 + g * 2;
            uint4 a0 = *(const uint4*)&qT[(ng * 16 + rowL) * 64 + ((c0 ^ r7) << 2)];
            uint4 a1 = *(const uint4*)&qT[(ng * 16 + rowL) * 64 + (((c0 + 1) ^ r7) << 2)];
            uint4 b0v = *(const uint4*)&kL[(mq * 16 + rowL) * 64 + ((c0 ^ r7) << 2)];
            uint4 b1v = *(const uint4*)&kL[(mq * 16 + rowL) * 64 + (((c0 + 1) ^ r7) << 2)];
            short8 qhi = mk_hi(a0, a1), qlo = mk_lo(a0, a1);
            short8 khi = mk_hi(b0v, b1v), klo = mk_lo(b0v, b1v);
            s1 = MFMA(qhi, khi, s1);
            s1 = MFMA(qhi, klo, s1);
            s1 = MFMA(qlo, khi, s1);
            int cg2 = ks * 4 + g;
            short8 qg = *(const short8*)&qgT[(ng * 16 + rowL) * 64 + ((cg2 ^ r7) << 3)];
            short8 kg2 = *(const short8*)&kgrL[(mq * 16 + rowL) * 64 + ((cg2 ^ r7) << 3)];
            s2 = MFMA(qg, kg2, s2);
        }
        SC_EACH12(SC_LOADC)
        SC_SCORE(0) SC_SCORE(1) SC_SCORE(2) SC_SCORE(3)
    }
    SC_EACH12(SC_OUT)
}

// pv: 512 thr / 8 waves; wave = (n-group 0/1) x (d-quad 0-3), 32-row n-tile.
// V staging + vt_s shared by both n-groups -> staging traffic halves.
__global__ __launch_bounds__(512) void sattn_pv(
    const unsigned* __restrict__ vpk, const float* __restrict__ Sbuf,
    unsigned* __restrict__ attno_pk, int b0)
{
    __shared__ unsigned short P_s[32 * 64];
    __shared__ unsigned vt_s[64 * 64];
    __shared__ float mrun[32], lrun[32], cos_[32];

    const int tid = threadIdx.x;
    const int lane = tid & 63;
    const int w8 = tid >> 6;
    const int wd = w8 & 3;        // d-quad
    const int ng = w8 >> 2;       // n-group
    const int rowL = lane & 15;
    const int g = lane >> 4;
    const int r7 = rowL & 7;
    const int n0 = blockIdx.x * 32;
    const int o = blockIdx.y;
    const int z = blockIdx.z;
    const int b = b0 + z;
    const int srow = tid >> 4;    // 0..31
    const int sc4 = (tid & 15) * 4;

    if (tid < 32) { mrun[tid] = -1e30f; lrun[tid] = 0.f; }
    f32x4 acc = {0,0,0,0};
    const float* Srow = Sbuf + ((size_t)(z * 12 + o) * 1024 + n0 + srow) * 1024;
    const unsigned* vp = vpk + ((size_t)(b * 12 + o) << 16);
    __syncthreads();

    for (int m0 = 0; m0 < 1024; m0 += 64) {
        float4 sv = *(const float4*)&Srow[m0 + sc4];
        float mx = fmaxf(fmaxf(sv.x, sv.y), fmaxf(sv.z, sv.w));
        mx = fmaxf(mx, __shfl_xor(mx, 1, 64));
        mx = fmaxf(mx, __shfl_xor(mx, 2, 64));
        mx = fmaxf(mx, __shfl_xor(mx, 4, 64));
        mx = fmaxf(mx, __shfl_xor(mx, 8, 64));
        float mo = mrun[srow];
        float mn = fmaxf(mo, mx);
        float co = expf(mo - mn);
        float p0 = expf(sv.x - mn), p1 = expf(sv.y - mn), p2 = expf(sv.z - mn), p3 = expf(sv.w - mn);
        unsigned u0 = bf16r(p0), u1 = bf16r(p1), u2 = bf16r(p2), u3 = bf16r(p3);
        {
            ushort4 pw = make_ushort4((unsigned short)u0, (unsigned short)u1,
                                      (unsigned short)u2, (unsigned short)u3);
            *(ushort4*)&P_s[srow * 64 + (((sc4 >> 3) ^ (srow & 7)) << 3) + (sc4 & 7)] = pw;
        }
        float ps = __uint_as_float(u0 << 16) + __uint_as_float(u1 << 16)
                 + __uint_as_float(u2 << 16) + __uint_as_float(u3 << 16);
        ps += __shfl_xor(ps, 1, 64); ps += __shfl_xor(ps, 2, 64);
        ps += __shfl_xor(ps, 4, 64); ps += __shfl_xor(ps, 8, 64);
        if ((lane & 15) == 0) {
            mrun[srow] = mn;
            cos_[srow] = co;
            lrun[srow] = lrun[srow] * co + ps;
        }
        // stage V^T (shared across both n-groups): 512 thr x 2 chunks
#pragma unroll
        for (int e = 0; e < 2; e++) {
            int d_ = tid & 63;
            int mb = (tid >> 6) * 4 + 32 * e;
            int mc = (tid >> 6) + 8 * e;
            uint4 v = ld4v(vp + (size_t)m0 * 64, mb, d_);
            *(uint4*)&vt_s[d_ * 64 + ((mc ^ (d_ & 15)) << 2)] = v;
        }
        __syncthreads();
        {
            float c0_ = cos_[ng * 16 + g * 4 + 0], c1_ = cos_[ng * 16 + g * 4 + 1];
            float c2_ = cos_[ng * 16 + g * 4 + 2], c3_ = cos_[ng * 16 + g * 4 + 3];
            acc[0] *= c0_; acc[1] *= c1_; acc[2] *= c2_; acc[3] *= c3_;
        }
        const int d_ = wd * 16 + rowL;
        const unsigned* vrow = &vt_s[d_ * 64];
#pragma unroll
        for (int kk = 0; kk < 2; kk++) {
            int mc8 = kk * 4 + g;
            short8 pa = *(const short8*)&P_s[(ng * 16 + rowL) * 64 + ((mc8 ^ r7) << 3)];
            int c0 = kk * 8 + g * 2;
            uint4 b0v = *(const uint4*)&vrow[((c0 ^ (d_ & 15)) << 2)];
            uint4 b1v = *(const uint4*)&vrow[(((c0 + 1) ^ (d_ & 15)) << 2)];
            short8 vh = mk_hi(b0v, b1v), vl = mk_lo(b0v, b1v);
            acc = MFMA(pa, vh, acc);
            acc = MFMA(pa, vl, acc);
        }
        __syncthreads();
    }
#pragma unroll
    for (int r = 0; r < 4; r++) {
        int row = ng * 16 + g * 4 + r;
        size_t idx = ((size_t)(b * 1024 + n0 + row)) * 768 + o * 64 + wd * 16 + rowL;
        attno_pk[idx] = packhl(acc[r] / lrun[row]);
    }
}

extern "C" void kernel_launch(void* const* d_in, const int* in_sizes, int n_in,
                              void* d_out, int out_size, void* d_ws, size_t ws_size,
                              hipStream_t stream) {
    const float* x          = (const float*)d_in[0];
    const float* qkv_w      = (const float*)d_in[1];
    const float* qkv_b      = (const float*)d_in[2];
    const float* proj_w     = (const float*)d_in[3];
    const float* proj_b     = (const float*)d_in[4];
    const float* scale      = (const float*)d_in[5];
    const float* riem_scale = (const float*)d_in[6];
    const float* grass_scale= (const float*)d_in[7];
    const float* conv_w     = (const float*)d_in[8];
    const float* conv_b     = (const float*)d_in[9];
    const float* bn_gamma   = (const float*)d_in[10];
    const float* bn_beta    = (const float*)d_in[11];
    const float* bn_mean    = (const float*)d_in[12];
    const float* bn_var     = (const float*)d_in[13];
    float* out = (float*)d_out;

    float* q   = (float*)d_ws;
    float* k   = q + 3145728;
    unsigned* qpk = (unsigned*)(k + 3145728);
    unsigned* kpk = qpk + 3145728;
    unsigned* vpk = kpk + 3145728;
    unsigned short* qgrh = (unsigned short*)(vpk + 3145728);
    unsigned short* kgrh = qgrh + 3145728;
    float* qn4 = (float*)(kgrh + 3145728);
    float* kn4 = qn4 + 49152;
    unsigned* attno_pk = (unsigned*)q;   // aliases q (q f32 dead after qr_fact)
    unsigned* ppk = (unsigned*)k;        // packed proj_w (k f32 dead after qr_fact)

    const size_t BASE = 75890688ull;
    const size_t SB1  = 50331648ull;
    float* Sbuf = (float*)((char*)d_ws + BASE);
    unsigned* xpk_ = (unsigned*)((char*)d_ws + BASE);          // packed x (12.58MB)
    unsigned* wpk_ = xpk_ + 3145728;                           // packed qkv_w (7.08MB)
    unsigned* Vpk2 = (unsigned*)((char*)d_ws + BASE);          // qr V (25.2MB), after xpk dead
    float* Wg   = (float*)(Vpk2 + 96 * 65536);
    float* taug = Wg + 96 * 4096;
    float* Gpart = taug + 96 * 64;
    const bool full = (ws_size >= BASE + 4 * SB1);   // measured false on this harness

    hipLaunchKernelGGL(pack_f32, dim3(3072), dim3(256), 0, stream, x, xpk_, 786432);
    hipLaunchKernelGGL(pack_f32, dim3(1728), dim3(256), 0, stream, qkv_w, wpk_, 442368);
    hipLaunchKernelGGL(qkv_mfma, dim3(36, 128), dim3(256), 0, stream,
                       xpk_, wpk_, qkv_b, q, k, qpk, kpk, vpk);
    hipLaunchKernelGGL(row_norms, dim3(24576), dim3(256), 0, stream, q, k, qn4, kn4);

    hipLaunchKernelGGL(qr_fact, dim3(96), dim3(1024), 0, stream, q, k, Vpk2, taug);
    hipLaunchKernelGGL(qr_gpart, dim3(96, 4), dim3(256), 0, stream, Vpk2, Gpart);
    hipLaunchKernelGGL(qr_tw2, dim3(96), dim3(256), 0, stream, Vpk2, taug, Gpart, Wg);
    hipLaunchKernelGGL(qr_formq, dim3(96, 16), dim3(256), 0, stream, Vpk2, Wg, qgrh, kgrh);

    hipLaunchKernelGGL(pack_f32, dim3(576), dim3(256), 0, stream, proj_w, ppk, 147456);

    if (full) {
        hipLaunchKernelGGL(sattn_scores, dim3(16, 32, 4), dim3(512), 0, stream,
                           qpk, kpk, qgrh, kgrh, qn4, kn4, conv_w, conv_b,
                           bn_gamma, bn_beta, bn_mean, bn_var,
                           scale, riem_scale, grass_scale, Sbuf, 0);
        hipLaunchKernelGGL(sattn_pv, dim3(32, 12, 4), dim3(512), 0, stream,
                           vpk, Sbuf, attno_pk, 0);
    } else {
        for (int b = 0; b < 4; b++) {
            hipLaunchKernelGGL(sattn_scores, dim3(16, 32, 1), dim3(512), 0, stream,
                               qpk, kpk, qgrh, kgrh, qn4, kn4, conv_w, conv_b,
                               bn_gamma, bn_beta, bn_mean, bn_var,
                               scale, riem_scale, grass_scale, Sbuf, b);
            hipLaunchKernelGGL(sattn_pv, dim3(32, 12, 1), dim3(512), 0, stream,
                               vpk, Sbuf, attno_pk, b);
        }
    }

    hipLaunchKernelGGL(proj_mfma, dim3(12, 128), dim3(256), 0, stream,
                       attno_pk, ppk, proj_b, out);
}

// Round 20
// 595.551 us; speedup vs baseline: 1.0148x; 1.0148x over previous
//
#include <hip/hip_runtime.h>
#include <math.h>

// B=4, N=1024, C=768, H=12, D=64
// ws: q[12.58MB] k qpk kpk vpk qgrh kgrh qn4 kn4  (= 75,890,688 B base)
// BASE region reused serially: {xpk,wpk} -> {Vpk2,Wg,taug,Gpart} -> Sbuf(per-batch).
// ppk lives in k region (k f32 dead after qr_fact). attno_pk aliases q region.
// Round-18 best-known configuration (597 us): scores 32-row/512thr, pv 16-row/256thr.

typedef __attribute__((ext_vector_type(8))) short short8;
typedef __attribute__((ext_vector_type(4))) float f32x4;

__device__ __forceinline__ unsigned bf16r(float x) {
    unsigned u = __float_as_uint(x);
    return (u + 0x7FFFu + ((u >> 16) & 1u)) >> 16;
}
__device__ __forceinline__ unsigned packhl(float x) {
    unsigned u = __float_as_uint(x);
    unsigned hi = (u + 0x7FFFu + ((u >> 16) & 1u)) & 0xFFFF0000u;
    float lo = x - __uint_as_float(hi);
    unsigned ul = __float_as_uint(lo);
    unsigned l16 = (ul + 0x7FFFu + ((ul >> 16) & 1u)) >> 16;
    return hi | (l16 & 0xFFFFu);
}
__device__ __forceinline__ float unpackhl(unsigned u) {
    return __uint_as_float(u & 0xFFFF0000u) + __uint_as_float(u << 16);
}
union U4S8 { uint4 u; short8 s; };
__device__ __forceinline__ short8 mk_hi(uint4 a, uint4 b) {
    U4S8 r;
    r.u.x = __builtin_amdgcn_perm(a.y, a.x, 0x07060302);
    r.u.y = __builtin_amdgcn_perm(a.w, a.z, 0x07060302);
    r.u.z = __builtin_amdgcn_perm(b.y, b.x, 0x07060302);
    r.u.w = __builtin_amdgcn_perm(b.w, b.z, 0x07060302);
    return r.s;
}
__device__ __forceinline__ short8 mk_lo(uint4 a, uint4 b) {
    U4S8 r;
    r.u.x = __builtin_amdgcn_perm(a.y, a.x, 0x05040100);
    r.u.y = __builtin_amdgcn_perm(a.w, a.z, 0x05040100);
    r.u.z = __builtin_amdgcn_perm(b.y, b.x, 0x05040100);
    r.u.w = __builtin_amdgcn_perm(b.w, b.z, 0x05040100);
    return r.s;
}
__device__ __forceinline__ uint4 ld4v(const unsigned* vp, int mbase, int d) {
    uint4 r;
    r.x = vp[(size_t)(mbase + 0) * 64 + d];
    r.y = vp[(size_t)(mbase + 1) * 64 + d];
    r.z = vp[(size_t)(mbase + 2) * 64 + d];
    r.w = vp[(size_t)(mbase + 3) * 64 + d];
    return r;
}
#define MFMA(a,b,c) __builtin_amdgcn_mfma_f32_16x16x32_bf16(a, b, c, 0, 0, 0)

// ---------------- pack: f32 -> hi|lo packed u32 ----------------
__global__ __launch_bounds__(256) void pack_f32(
    const float* __restrict__ src, unsigned* __restrict__ dst, int n4)
{
    int i = blockIdx.x * 256 + threadIdx.x;
    if (i < n4) {
        float4 v = *(const float4*)&src[(size_t)i * 4];
        uint4 o;
        o.x = packhl(v.x); o.y = packhl(v.y); o.z = packhl(v.z); o.w = packhl(v.w);
        *(uint4*)&dst[(size_t)i * 4] = o;
    }
}

// ---------------- K1-MFMA: qkv = x @ w^T + b (32x64 tile) ----------------
__global__ __launch_bounds__(256) void qkv_mfma(
    const unsigned* __restrict__ xpk, const unsigned* __restrict__ wpk,
    const float* __restrict__ bias,
    float* __restrict__ q, float* __restrict__ k,
    unsigned* __restrict__ qpk, unsigned* __restrict__ kpk, unsigned* __restrict__ vpk)
{
    __shared__ unsigned xT[32 * 64];
    __shared__ unsigned wT[64 * 64];
    const int tid = threadIdx.x;
    const int lane = tid & 63;
    const int w = tid >> 6;
    const int rowL = lane & 15;
    const int g = lane >> 4;
    const int r7 = rowL & 7;
    const int n0 = blockIdx.x * 64;
    const int m0 = blockIdx.y * 32;
    f32x4 accA = {0,0,0,0}, accB = {0,0,0,0};

    for (int kk0 = 0; kk0 < 768; kk0 += 64) {
        __syncthreads();
#pragma unroll
        for (int e = 0; e < 2; e++) {
            int ci = tid + 256 * e; int R = ci >> 4, c = ci & 15;
            uint4 v = *(const uint4*)&xpk[(size_t)(m0 + R) * 768 + kk0 + c * 4];
            *(uint4*)&xT[R * 64 + ((c ^ (R & 7)) << 2)] = v;
        }
#pragma unroll
        for (int e = 0; e < 4; e++) {
            int ci = tid + 256 * e; int R = ci >> 4, c = ci & 15;
            uint4 v = *(const uint4*)&wpk[(size_t)(n0 + R) * 768 + kk0 + c * 4];
            *(uint4*)&wT[R * 64 + ((c ^ (R & 7)) << 2)] = v;
        }
        __syncthreads();
#pragma unroll
        for (int ks = 0; ks < 2; ks++) {
            int c0 = ks * 8 + g * 2;
            uint4 b0 = *(const uint4*)&wT[(w * 16 + rowL) * 64 + ((c0 ^ r7) << 2)];
            uint4 b1 = *(const uint4*)&wT[(w * 16 + rowL) * 64 + (((c0 + 1) ^ r7) << 2)];
            short8 whi = mk_hi(b0, b1), wlo = mk_lo(b0, b1);
            uint4 a0 = *(const uint4*)&xT[rowL * 64 + ((c0 ^ r7) << 2)];
            uint4 a1 = *(const uint4*)&xT[rowL * 64 + (((c0 + 1) ^ r7) << 2)];
            short8 xhi = mk_hi(a0, a1), xlo = mk_lo(a0, a1);
            accA = MFMA(xhi, whi, accA);
            accA = MFMA(xhi, wlo, accA);
            accA = MFMA(xlo, whi, accA);
            uint4 a2 = *(const uint4*)&xT[(16 + rowL) * 64 + ((c0 ^ r7) << 2)];
            uint4 a3 = *(const uint4*)&xT[(16 + rowL) * 64 + (((c0 + 1) ^ r7) << 2)];
            short8 xhi2 = mk_hi(a2, a3), xlo2 = mk_lo(a2, a3);
            accB = MFMA(xhi2, whi, accB);
            accB = MFMA(xhi2, wlo, accB);
            accB = MFMA(xlo2, whi, accB);
        }
    }
    const int col = n0 + w * 16 + rowL;
    const float bv = bias[col];
    const int s = (n0 >= 1536) ? 2 : ((n0 >= 768) ? 1 : 0);
    const int hc = col - s * 768;
    const int head = hc >> 6;
    const int cin = hc & 63;
#pragma unroll
    for (int half = 0; half < 2; half++) {
        f32x4 acc = half ? accB : accA;
#pragma unroll
        for (int r = 0; r < 4; r++) {
            int row = m0 + half * 16 + g * 4 + r;
            int bb = row >> 10, n = row & 1023;
            size_t idx = ((size_t)(bb * 12 + head) << 16) + ((size_t)n << 6) + cin;
            float val = acc[r] + bv;
            if (s == 0)      { q[idx] = val; qpk[idx] = packhl(val); }
            else if (s == 1) { k[idx] = val; kpk[idx] = packhl(val); }
            else             { vpk[idx] = packhl(val); }
        }
    }
}

// ---------------- K4-MFMA: out = attno_pk @ ppk^T + proj_b ----------------
__global__ __launch_bounds__(256) void proj_mfma(
    const unsigned* __restrict__ apk, const unsigned* __restrict__ wpk,
    const float* __restrict__ bias, float* __restrict__ out)
{
    __shared__ unsigned xT[32 * 64];
    __shared__ unsigned wT[64 * 64];
    const int tid = threadIdx.x;
    const int lane = tid & 63;
    const int w = tid >> 6;
    const int rowL = lane & 15;
    const int g = lane >> 4;
    const int r7 = rowL & 7;
    const int n0 = blockIdx.x * 64;
    const int m0 = blockIdx.y * 32;
    f32x4 accA = {0,0,0,0}, accB = {0,0,0,0};

    for (int kk0 = 0; kk0 < 768; kk0 += 64) {
        __syncthreads();
#pragma unroll
        for (int e = 0; e < 2; e++) {
            int ci = tid + 256 * e; int R = ci >> 4, c = ci & 15;
            uint4 v = *(const uint4*)&apk[(size_t)(m0 + R) * 768 + kk0 + c * 4];
            *(uint4*)&xT[R * 64 + ((c ^ (R & 7)) << 2)] = v;
        }
#pragma unroll
        for (int e = 0; e < 4; e++) {
            int ci = tid + 256 * e; int R = ci >> 4, c = ci & 15;
            uint4 v = *(const uint4*)&wpk[(size_t)(n0 + R) * 768 + kk0 + c * 4];
            *(uint4*)&wT[R * 64 + ((c ^ (R & 7)) << 2)] = v;
        }
        __syncthreads();
#pragma unroll
        for (int ks = 0; ks < 2; ks++) {
            int c0 = ks * 8 + g * 2;
            uint4 b0 = *(const uint4*)&wT[(w * 16 + rowL) * 64 + ((c0 ^ r7) << 2)];
            uint4 b1 = *(const uint4*)&wT[(w * 16 + rowL) * 64 + (((c0 + 1) ^ r7) << 2)];
            short8 whi = mk_hi(b0, b1), wlo = mk_lo(b0, b1);
            uint4 a0 = *(const uint4*)&xT[rowL * 64 + ((c0 ^ r7) << 2)];
            uint4 a1 = *(const uint4*)&xT[rowL * 64 + (((c0 + 1) ^ r7) << 2)];
            short8 xhi = mk_hi(a0, a1), xlo = mk_lo(a0, a1);
            accA = MFMA(xhi, whi, accA);
            accA = MFMA(xhi, wlo, accA);
            accA = MFMA(xlo, whi, accA);
            uint4 a2 = *(const uint4*)&xT[(16 + rowL) * 64 + ((c0 ^ r7) << 2)];
            uint4 a3 = *(const uint4*)&xT[(16 + rowL) * 64 + (((c0 + 1) ^ r7) << 2)];
            short8 xhi2 = mk_hi(a2, a3), xlo2 = mk_lo(a2, a3);
            accB = MFMA(xhi2, whi, accB);
            accB = MFMA(xhi2, wlo, accB);
            accB = MFMA(xlo2, whi, accB);
        }
    }
    const int col = n0 + w * 16 + rowL;
    const float bv = bias[col];
#pragma unroll
    for (int half = 0; half < 2; half++) {
        f32x4 acc = half ? accB : accA;
#pragma unroll
        for (int r = 0; r < 4; r++) {
            int row = m0 + half * 16 + g * 4 + r;
            out[(size_t)row * 768 + col] = acc[r] + bv;
        }
    }
}

// ---------------- K1b: squared row norms ----------------
__global__ __launch_bounds__(256) void row_norms(
    const float* __restrict__ q, const float* __restrict__ k,
    float* __restrict__ qn4, float* __restrict__ kn4)
{
    int wid = blockIdx.x * 4 + (threadIdx.x >> 6);
    int lane = threadIdx.x & 63;
    const float* src; float* dst; int r;
    if (wid < 49152) { src = q; dst = qn4; r = wid; }
    else             { src = k; dst = kn4; r = wid - 49152; }
    float xv = src[(size_t)r * 64 + lane];
    float s = xv * xv;
#pragma unroll
    for (int m = 1; m < 64; m <<= 1) s += __shfl_xor(s, m, 64);
    if (lane == 0) dst[r] = s * s;
}

// ---------------- K2a: Householder factorization (LAPACK signs) ----------------
__global__ __launch_bounds__(1024)
__attribute__((amdgpu_waves_per_eu(4, 4)))
void qr_fact(const float* __restrict__ q, const float* __restrict__ k,
             unsigned* __restrict__ Vp_, float* __restrict__ taug)
{
    const int id = blockIdx.x;
    const float* src = (id & 1) ? k : q;
    src += (size_t)(id >> 1) << 16;
    unsigned* Vp = Vp_ + (size_t)id * 65536;
    const int tid = threadIdx.x;
    const int lane = tid & 63;
    const int w = tid >> 6;
    __shared__ float vbufA[1024];
    __shared__ float vbufB[1024];
    __shared__ float taub[64];

    float a[4][16];
#pragma unroll
    for (int c = 0; c < 4; c++)
#pragma unroll
        for (int i = 0; i < 16; i++)
            a[c][i] = src[(i * 64 + lane) * 64 + 4 * w + c];

    if (w == 0) {
        float part = 0.f;
#pragma unroll
        for (int i = 0; i < 16; i++) part += a[0][i] * a[0][i];
#pragma unroll
        for (int m = 1; m < 64; m <<= 1) part += __shfl_xor(part, m, 64);
        float sigma = part;
        float xd = __shfl(a[0][0], 0, 64);
        float nrm = sqrtf(sigma);
        float beta = (xd >= 0.f) ? -nrm : nrm;
        float vd = xd - beta;
        float vtv = (sigma - xd * xd) + vd * vd;
        float tau2 = (vtv > 0.f) ? 2.f / vtv : 0.f;
        if (lane == 0) a[0][0] = vd;
#pragma unroll
        for (int i = 0; i < 16; i++) vbufA[i * 64 + lane] = a[0][i];
        if (lane == 0) taub[0] = tau2;
    }
    __syncthreads();

    for (int d = 0; d < 64; d++) {
        const int jb = 4 * w;
        if (jb + 3 > d) {
            float* vb = (d & 1) ? vbufB : vbufA;
            float vr[16];
#pragma unroll
            for (int i = 0; i < 16; i++) vr[i] = vb[i * 64 + lane];
            float t2 = taub[d];
            float dp0 = 0.f, dp1 = 0.f, dp2 = 0.f, dp3 = 0.f;
#pragma unroll
            for (int i = 0; i < 16; i++) {
                dp0 += vr[i] * a[0][i];
                dp1 += vr[i] * a[1][i];
                dp2 += vr[i] * a[2][i];
                dp3 += vr[i] * a[3][i];
            }
#pragma unroll
            for (int m = 1; m < 64; m <<= 1) {
                dp0 += __shfl_xor(dp0, m, 64);
                dp1 += __shfl_xor(dp1, m, 64);
                dp2 += __shfl_xor(dp2, m, 64);
                dp3 += __shfl_xor(dp3, m, 64);
            }
            float s0 = t2 * dp0, s1 = t2 * dp1, s2 = t2 * dp2, s3 = t2 * dp3;
            if (jb + 0 > d) {
#pragma unroll
                for (int i = 0; i < 16; i++) a[0][i] -= s0 * vr[i];
            }
            if (jb + 1 > d) {
#pragma unroll
                for (int i = 0; i < 16; i++) a[1][i] -= s1 * vr[i];
            }
            if (jb + 2 > d) {
#pragma unroll
                for (int i = 0; i < 16; i++) a[2][i] -= s2 * vr[i];
            }
            {
#pragma unroll
                for (int i = 0; i < 16; i++) a[3][i] -= s3 * vr[i];
            }
        }
        if (d < 63) {
            const int dn = d + 1;
            if (w == (dn >> 2)) {
                const int cd = dn & 3;
#pragma unroll
                for (int c = 0; c < 4; c++) if (c == cd) {
                    float part = 0.f;
#pragma unroll
                    for (int i = 0; i < 16; i++) {
                        int r = i * 64 + lane;
                        float xx = a[c][i];
                        part += (r >= dn) ? xx * xx : 0.f;
                    }
#pragma unroll
                    for (int m = 1; m < 64; m <<= 1) part += __shfl_xor(part, m, 64);
                    float sigma = part;
                    float xd = __shfl(a[c][0], dn, 64);
                    float nrm = sqrtf(sigma);
                    float beta = (xd >= 0.f) ? -nrm : nrm;
                    float vd = xd - beta;
                    float vtv = (sigma - xd * xd) + vd * vd;
                    float tau2 = (vtv > 0.f) ? 2.f / vtv : 0.f;
                    if (lane == dn) a[c][0] = vd;
                    float* vbn = (dn & 1) ? vbufB : vbufA;
#pragma unroll
                    for (int i = 0; i < 16; i++) {
                        int r = i * 64 + lane;
                        vbn[i * 64 + lane] = (r < dn) ? 0.f : a[c][i];
                    }
                    if (lane == 0) taub[dn] = tau2;
                }
            }
        }
        __syncthreads();
    }

    if (tid < 64) taug[id * 64 + tid] = taub[tid];
#pragma unroll
    for (int c = 0; c < 4; c++) {
        int j = 4 * w + c;
#pragma unroll
        for (int i = 0; i < 16; i++) {
            int r = i * 64 + lane;
            float vv = (r < j) ? 0.f : a[c][i];
            Vp[(size_t)j * 1024 + r] = packhl(vv);
        }
    }
}

// ---------------- K2b-1: partial G = V^T V over 256-row slab (MFMA) ----------------
__global__ __launch_bounds__(256) void qr_gpart(
    const unsigned* __restrict__ Vp_, float* __restrict__ Gpart)
{
    const int id = blockIdx.x;
    const int sl = blockIdx.y;
    const unsigned* Vp = Vp_ + (size_t)id * 65536;
    __shared__ unsigned Vc[64 * 32];
    const int tid = threadIdx.x;
    const int lane = tid & 63;
    const int w = tid >> 6;
    const int rowL = lane & 15;
    const int g = lane >> 4;

    f32x4 acc0 = {0,0,0,0}, acc1 = {0,0,0,0}, acc2 = {0,0,0,0}, acc3 = {0,0,0,0};
    for (int r0 = sl * 256; r0 < sl * 256 + 256; r0 += 32) {
        __syncthreads();
#pragma unroll
        for (int e = 0; e < 2; e++) {
            int ci = tid + 256 * e;
            int row = ci >> 3, c = ci & 7;
            uint4 v = *(const uint4*)&Vp[(size_t)row * 1024 + r0 + c * 4];
            *(uint4*)&Vc[row * 32 + ((c ^ (row & 7)) << 2)] = v;
        }
        __syncthreads();
        int ra = w * 16 + rowL;
        uint4 a0 = *(const uint4*)&Vc[ra * 32 + (((g * 2) ^ (ra & 7)) << 2)];
        uint4 a1 = *(const uint4*)&Vc[ra * 32 + (((g * 2 + 1) ^ (ra & 7)) << 2)];
        short8 Ahi = mk_hi(a0, a1), Alo = mk_lo(a0, a1);
#define GDO(jt, accv) { int rb = jt * 16 + rowL; \
        uint4 b0 = *(const uint4*)&Vc[rb * 32 + (((g * 2) ^ (rb & 7)) << 2)]; \
        uint4 b1 = *(const uint4*)&Vc[rb * 32 + (((g * 2 + 1) ^ (rb & 7)) << 2)]; \
        short8 Bhi = mk_hi(b0, b1), Blo = mk_lo(b0, b1); \
        accv = MFMA(Ahi, Bhi, accv); accv = MFMA(Ahi, Blo, accv); accv = MFMA(Alo, Bhi, accv); }
        GDO(0, acc0) GDO(1, acc1) GDO(2, acc2) GDO(3, acc3)
#undef GDO
    }
    float* dst = Gpart + ((size_t)(id * 4 + sl) << 12);
#define GWR(jt, accv) { \
    dst[(w * 16 + g * 4 + 0) * 64 + jt * 16 + rowL] = accv[0]; \
    dst[(w * 16 + g * 4 + 1) * 64 + jt * 16 + rowL] = accv[1]; \
    dst[(w * 16 + g * 4 + 2) * 64 + jt * 16 + rowL] = accv[2]; \
    dst[(w * 16 + g * 4 + 3) * 64 + jt * 16 + rowL] = accv[3]; }
    GWR(0, acc0) GWR(1, acc1) GWR(2, acc2) GWR(3, acc3)
#undef GWR
}

// ---------------- K2b-2: W via back-substitution ----------------
__global__ __launch_bounds__(256) void qr_tw2(
    const unsigned* __restrict__ Vp_, const float* __restrict__ taug,
    const float* __restrict__ Gpart, float* __restrict__ Wg)
{
    const int id = blockIdx.x;
    const unsigned* Vp = Vp_ + (size_t)id * 65536;
    __shared__ float G_s[64 * 65];
    __shared__ float wbuf[64];
    __shared__ float tau_s[64];
    const int tid = threadIdx.x;
    if (tid < 64) tau_s[tid] = taug[id * 64 + tid];
    const float* Gp = Gpart + ((size_t)(id * 4) << 12);
#pragma unroll
    for (int e = 0; e < 16; e++) {
        int idx = tid + 256 * e;
        float sum = Gp[idx] + Gp[4096 + idx] + Gp[8192 + idx] + Gp[12288 + idx];
        G_s[(idx >> 6) * 65 + (idx & 63)] = sum;
    }
    const int i = tid >> 2;
    const int cq = tid & 3;
    float regA[16];
#pragma unroll
    for (int cc = 0; cc < 16; cc++)
        regA[cc] = unpackhl(Vp[(size_t)i * 1024 + cq * 16 + cc]);
    __syncthreads();
    for (int j = 63; j >= 0; j--) {
        if (i == j) {
            float tj = tau_s[j];
#pragma unroll
            for (int cc = 0; cc < 16; cc++) {
                regA[cc] *= tj;
                wbuf[cq * 16 + cc] = regA[cc];
            }
        }
        __syncthreads();
        if (i < j) {
            float gij = G_s[i * 65 + j];
#pragma unroll
            for (int cc = 0; cc < 16; cc++)
                regA[cc] = fmaf(-gij, wbuf[cq * 16 + cc], regA[cc]);
        }
        __syncthreads();
    }
#pragma unroll
    for (int cc = 0; cc < 16; cc++)
        Wg[(size_t)id * 4096 + i * 64 + cq * 16 + cc] = regA[cc];
}

// ---------------- K2c: Q = [I;0] - V W, bf16 output ----------------
__global__ __launch_bounds__(256) void qr_formq(
    const unsigned* __restrict__ Vp_, const float* __restrict__ Wg,
    unsigned short* __restrict__ qgrh, unsigned short* __restrict__ kgrh)
{
    const int id = blockIdx.x;
    const int rb = blockIdx.y;
    const unsigned* Vp = Vp_ + (size_t)id * 65536;
    const float* Wm = Wg + (size_t)id * 4096;
    unsigned short* dst = ((id & 1) ? kgrh : qgrh) + ((size_t)(id >> 1) << 16);
    __shared__ float Vl[64 * 65];
    __shared__ float Wl[64 * 64];
    const int tid = threadIdx.x;
    const int rbase = rb * 64;
#pragma unroll
    for (int e = 0; e < 16; e++) {
        int idx = tid + 256 * e;
        int j = idx >> 6, rl = idx & 63;
        Vl[rl * 65 + j] = unpackhl(Vp[(size_t)j * 1024 + rbase + rl]);
        Wl[idx] = Wm[idx];
    }
    __syncthreads();
    const int rl = tid >> 2;
    const int cg = (tid & 3) << 4;
    const int rglob = rbase + rl;
    unsigned short outv[16];
#pragma unroll
    for (int cc = 0; cc < 16; cc++) {
        int c = cg + cc;
        float s = (rglob == c) ? 1.f : 0.f;
        for (int j = 0; j < 64; j++) s -= Vl[rl * 65 + j] * Wl[j * 64 + c];
        outv[cc] = (unsigned short)bf16r(s);
    }
#pragma unroll
    for (int cc = 0; cc < 16; cc += 4)
        *(ushort4*)&dst[(size_t)rglob * 64 + cg + cc] = *(ushort4*)&outv[cc];
}

// ================= SPLIT ATTENTION PATH =================
// scores: 512 thr / 8 waves; wave = (n-group 0/1) x (m-quad 0-3), 32-row n-tile.
#define SC_EACH12(F) F(0) F(1) F(2) F(3) F(4) F(5) F(6) F(7) F(8) F(9) F(10) F(11)
#define SC_DECLY(o) float y##o##_0 = 0.f, y##o##_1 = 0.f, y##o##_2 = 0.f, y##o##_3 = 0.f;
#define SC_LOADC(o) const float cA##o = cw[o * 36 + h], \
                                cB##o = cw[o * 36 + 12 + h], \
                                cC##o = cw[o * 36 + 24 + h];
#define SC_CONV1(o,r) y##o##_##r = fmaf(cA##o, att, fmaf(cB##o, rie, fmaf(cC##o, gra, y##o##_##r)));
#define SC_CONVROW(r) SC_CONV1(0,r) SC_CONV1(1,r) SC_CONV1(2,r) SC_CONV1(3,r) SC_CONV1(4,r) SC_CONV1(5,r) \
                      SC_CONV1(6,r) SC_CONV1(7,r) SC_CONV1(8,r) SC_CONV1(9,r) SC_CONV1(10,r) SC_CONV1(11,r)
#define SC_SCORE(r) { \
    float qk = s1[r], gr = s2[r]; \
    float qn4v = qn4s[ng * 16 + g * 4 + r]; \
    float att = qk * scale; \
    float d2 = qn4v + kn4v - 2.f * qk * qk; \
    float rie = -sqrtf(fmaxf(d2, 0.f) + 1e-8f) * riem_scale; \
    float gra = gr * gr * grass_scale; \
    SC_CONVROW(r) }
#define SC_OUT(o) { \
    float inv = bn_gamma[o] * rsqrtf(bn_var[o] + 1e-5f); \
    float Bb = fmaf(conv_b[o] - bn_mean[o], inv, bn_beta[o]); \
    float* dst = Sbuf + ((size_t)(z * 12 + o) * 1024 + n0 + ng * 16) * 1024 + m0 + mq * 16 + rowL; \
    dst[(size_t)(g * 4 + 0) * 1024] = fmaf(y##o##_0, inv, Bb); \
    dst[(size_t)(g * 4 + 1) * 1024] = fmaf(y##o##_1, inv, Bb); \
    dst[(size_t)(g * 4 + 2) * 1024] = fmaf(y##o##_2, inv, Bb); \
    dst[(size_t)(g * 4 + 3) * 1024] = fmaf(y##o##_3, inv, Bb); }

__global__ __launch_bounds__(512) void sattn_scores(
    const unsigned* __restrict__ qpk, const unsigned* __restrict__ kpk,
    const unsigned short* __restrict__ qgrh, const unsigned short* __restrict__ kgrh,
    const float* __restrict__ qn4g, const float* __restrict__ kn4g,
    const float* __restrict__ cw, const float* __restrict__ conv_b,
    const float* __restrict__ bn_gamma, const float* __restrict__ bn_beta,
    const float* __restrict__ bn_mean, const float* __restrict__ bn_var,
    const float* __restrict__ scale_p, const float* __restrict__ riem_p,
    const float* __restrict__ grass_p, float* __restrict__ Sbuf, int b0)
{
    __shared__ unsigned qT[32 * 64];
    __shared__ unsigned short qgT[32 * 64];
    __shared__ unsigned kL[64 * 64];
    __shared__ unsigned short kgrL[64 * 64];
    __shared__ float qn4s[32];
    __shared__ float kn4s[64];

    const int tid = threadIdx.x;
    const int lane = tid & 63;
    const int w8 = tid >> 6;
    const int mq = w8 & 3;
    const int ng = w8 >> 2;
    const int rowL = lane & 15;
    const int g = lane >> 4;
    const int r7 = rowL & 7;
    const int m0 = blockIdx.x * 64;
    const int n0 = blockIdx.y * 32;
    const int z = blockIdx.z;
    const int b = b0 + z;
    const float scale = scale_p[0], riem_scale = riem_p[0], grass_scale = grass_p[0];

    SC_EACH12(SC_DECLY)

    for (int h = 0; h < 12; h++) {
        __syncthreads();
        {
            int R = tid >> 4, c = tid & 15;
            uint4 v = *(const uint4*)&qpk[((size_t)(b * 12 + h) << 16) + (size_t)(n0 + R) * 64 + c * 4];
            *(uint4*)&qT[R * 64 + ((c ^ (R & 7)) << 2)] = v;
        }
        if (tid < 256) {
            int R = tid >> 3, c = tid & 7;
            uint4 v = *(const uint4*)&qgrh[((size_t)(b * 12 + h) << 16) + (size_t)(n0 + R) * 64 + c * 8];
            *(uint4*)&qgT[R * 64 + ((c ^ (R & 7)) << 3)] = v;
        }
#pragma unroll
        for (int e = 0; e < 2; e++) {
            int ci = tid + 512 * e; int m = ci >> 4, c = ci & 15;
            uint4 v = *(const uint4*)&kpk[((size_t)(b * 12 + h) << 16) + (size_t)(m0 + m) * 64 + c * 4];
            *(uint4*)&kL[m * 64 + ((c ^ (m & 7)) << 2)] = v;
        }
        {
            int ci = tid; int m = ci >> 3, c = ci & 7;
            uint4 v = *(const uint4*)&kgrh[((size_t)(b * 12 + h) << 16) + (size_t)(m0 + m) * 64 + c * 8];
            *(uint4*)&kgrL[m * 64 + ((c ^ (m & 7)) << 3)] = v;
        }
        if (tid < 64) kn4s[tid] = kn4g[(size_t)(b * 12 + h) * 1024 + m0 + tid];
        if (tid < 32) qn4s[tid] = qn4g[(size_t)(b * 12 + h) * 1024 + n0 + tid];
        __syncthreads();

        float kn4v = kn4s[mq * 16 + rowL];
        f32x4 s1 = {0,0,0,0}, s2 = {0,0,0,0};
#pragma unroll
        for (int ks = 0; ks < 2; ks++) {
            int c0 = ks * 8 + g * 2;
            uint4 a0 = *(const uint4*)&qT[(ng * 16 + rowL) * 64 + ((c0 ^ r7) << 2)];
            uint4 a1 = *(const uint4*)&qT[(ng * 16 + rowL) * 64 + (((c0 + 1) ^ r7) << 2)];
            uint4 b0v = *(const uint4*)&kL[(mq * 16 + rowL) * 64 + ((c0 ^ r7) << 2)];
            uint4 b1v = *(const uint4*)&kL[(mq * 16 + rowL) * 64 + (((c0 + 1) ^ r7) << 2)];
            short8 qhi = mk_hi(a0, a1), qlo = mk_lo(a0, a1);
            short8 khi = mk_hi(b0v, b1v), klo = mk_lo(b0v, b1v);
            s1 = MFMA(qhi, khi, s1);
            s1 = MFMA(qhi, klo, s1);
            s1 = MFMA(qlo, khi, s1);
            int cg2 = ks * 4 + g;
            short8 qg = *(const short8*)&qgT[(ng * 16 + rowL) * 64 + ((cg2 ^ r7) << 3)];
            short8 kg2 = *(const short8*)&kgrL[(mq * 16 + rowL) * 64 + ((cg2 ^ r7) << 3)];
            s2 = MFMA(qg, kg2, s2);
        }
        SC_EACH12(SC_LOADC)
        SC_SCORE(0) SC_SCORE(1) SC_SCORE(2) SC_SCORE(3)
    }
    SC_EACH12(SC_OUT)
}

// pv: 256 thr / 4 waves (wave = d-quad), 16-row n-tile (round-18 best form).
__global__ __launch_bounds__(256) void sattn_pv(
    const unsigned* __restrict__ vpk, const float* __restrict__ Sbuf,
    unsigned* __restrict__ attno_pk, int b0)
{
    __shared__ unsigned short P_s[16 * 64];
    __shared__ unsigned vt_s[64 * 64];
    __shared__ float mrun[16], lrun[16], cos_[16];

    const int tid = threadIdx.x;
    const int lane = tid & 63;
    const int w = tid >> 6;
    const int rowL = lane & 15;
    const int g = lane >> 4;
    const int r7 = rowL & 7;
    const int n0 = blockIdx.x * 16;
    const int o = blockIdx.y;
    const int z = blockIdx.z;
    const int b = b0 + z;
    const int srow = tid >> 4;
    const int sc4 = (tid & 15) * 4;

    if (tid < 16) { mrun[tid] = -1e30f; lrun[tid] = 0.f; }
    f32x4 acc = {0,0,0,0};
    const float* Srow = Sbuf + ((size_t)(z * 12 + o) * 1024 + n0 + srow) * 1024;
    const unsigned* vp = vpk + ((size_t)(b * 12 + o) << 16);
    __syncthreads();

    for (int m0 = 0; m0 < 1024; m0 += 64) {
        float4 sv = *(const float4*)&Srow[m0 + sc4];
        float mx = fmaxf(fmaxf(sv.x, sv.y), fmaxf(sv.z, sv.w));
        mx = fmaxf(mx, __shfl_xor(mx, 1, 64));
        mx = fmaxf(mx, __shfl_xor(mx, 2, 64));
        mx = fmaxf(mx, __shfl_xor(mx, 4, 64));
        mx = fmaxf(mx, __shfl_xor(mx, 8, 64));
        float mo = mrun[srow];
        float mn = fmaxf(mo, mx);
        float co = expf(mo - mn);
        float p0 = expf(sv.x - mn), p1 = expf(sv.y - mn), p2 = expf(sv.z - mn), p3 = expf(sv.w - mn);
        unsigned u0 = bf16r(p0), u1 = bf16r(p1), u2 = bf16r(p2), u3 = bf16r(p3);
        {
            ushort4 pw = make_ushort4((unsigned short)u0, (unsigned short)u1,
                                      (unsigned short)u2, (unsigned short)u3);
            *(ushort4*)&P_s[srow * 64 + (((sc4 >> 3) ^ (srow & 7)) << 3) + (sc4 & 7)] = pw;
        }
        float ps = __uint_as_float(u0 << 16) + __uint_as_float(u1 << 16)
                 + __uint_as_float(u2 << 16) + __uint_as_float(u3 << 16);
        ps += __shfl_xor(ps, 1, 64); ps += __shfl_xor(ps, 2, 64);
        ps += __shfl_xor(ps, 4, 64); ps += __shfl_xor(ps, 8, 64);
        if ((lane & 15) == 0) {
            mrun[srow] = mn;
            cos_[srow] = co;
            lrun[srow] = lrun[srow] * co + ps;
        }
#pragma unroll
        for (int e = 0; e < 4; e++) {
            int d_ = tid & 63;
            int mb = (tid >> 6) * 4 + 16 * e;
            int mc = (tid >> 6) + 4 * e;
            uint4 v = ld4v(vp + (size_t)m0 * 64, mb, d_);
            *(uint4*)&vt_s[d_ * 64 + ((mc ^ (d_ & 15)) << 2)] = v;
        }
        __syncthreads();
        {
            float c0_ = cos_[g * 4 + 0], c1_ = cos_[g * 4 + 1];
            float c2_ = cos_[g * 4 + 2], c3_ = cos_[g * 4 + 3];
            acc[0] *= c0_; acc[1] *= c1_; acc[2] *= c2_; acc[3] *= c3_;
        }
        const int d_ = w * 16 + rowL;
        const unsigned* vrow = &vt_s[d_ * 64];
#pragma unroll
        for (int kk = 0; kk < 2; kk++) {
            int mc8 = kk * 4 + g;
            short8 pa = *(const short8*)&P_s[rowL * 64 + ((mc8 ^ r7) << 3)];
            int c0 = kk * 8 + g * 2;
            uint4 b0v = *(const uint4*)&vrow[((c0 ^ (d_ & 15)) << 2)];
            uint4 b1v = *(const uint4*)&vrow[(((c0 + 1) ^ (d_ & 15)) << 2)];
            short8 vh = mk_hi(b0v, b1v), vl = mk_lo(b0v, b1v);
            acc = MFMA(pa, vh, acc);
            acc = MFMA(pa, vl, acc);
        }
        __syncthreads();
    }
#pragma unroll
    for (int r = 0; r < 4; r++) {
        int row = g * 4 + r;
        size_t idx = ((size_t)(b * 1024 + n0 + row)) * 768 + o * 64 + w * 16 + rowL;
        attno_pk[idx] = packhl(acc[r] / lrun[row]);
    }
}

extern "C" void kernel_launch(void* const* d_in, const int* in_sizes, int n_in,
                              void* d_out, int out_size, void* d_ws, size_t ws_size,
                              hipStream_t stream) {
    const float* x          = (const float*)d_in[0];
    const float* qkv_w      = (const float*)d_in[1];
    const float* qkv_b      = (const float*)d_in[2];
    const float* proj_w     = (const float*)d_in[3];
    const float* proj_b     = (const float*)d_in[4];
    const float* scale      = (const float*)d_in[5];
    const float* riem_scale = (const float*)d_in[6];
    const float* grass_scale= (const float*)d_in[7];
    const float* conv_w     = (const float*)d_in[8];
    const float* conv_b     = (const float*)d_in[9];
    const float* bn_gamma   = (const float*)d_in[10];
    const float* bn_beta    = (const float*)d_in[11];
    const float* bn_mean    = (const float*)d_in[12];
    const float* bn_var     = (const float*)d_in[13];
    float* out = (float*)d_out;

    float* q   = (float*)d_ws;
    float* k   = q + 3145728;
    unsigned* qpk = (unsigned*)(k + 3145728);
    unsigned* kpk = qpk + 3145728;
    unsigned* vpk = kpk + 3145728;
    unsigned short* qgrh = (unsigned short*)(vpk + 3145728);
    unsigned short* kgrh = qgrh + 3145728;
    float* qn4 = (float*)(kgrh + 3145728);
    float* kn4 = qn4 + 49152;
    unsigned* attno_pk = (unsigned*)q;   // aliases q (q f32 dead after qr_fact)
    unsigned* ppk = (unsigned*)k;        // packed proj_w (k f32 dead after qr_fact)

    const size_t BASE = 75890688ull;
    const size_t SB1  = 50331648ull;
    float* Sbuf = (float*)((char*)d_ws + BASE);
    unsigned* xpk_ = (unsigned*)((char*)d_ws + BASE);          // packed x (12.58MB)
    unsigned* wpk_ = xpk_ + 3145728;                           // packed qkv_w (7.08MB)
    unsigned* Vpk2 = (unsigned*)((char*)d_ws + BASE);          // qr V (25.2MB), after xpk dead
    float* Wg   = (float*)(Vpk2 + 96 * 65536);
    float* taug = Wg + 96 * 4096;
    float* Gpart = taug + 96 * 64;
    const bool full = (ws_size >= BASE + 4 * SB1);   // measured false on this harness

    hipLaunchKernelGGL(pack_f32, dim3(3072), dim3(256), 0, stream, x, xpk_, 786432);
    hipLaunchKernelGGL(pack_f32, dim3(1728), dim3(256), 0, stream, qkv_w, wpk_, 442368);
    hipLaunchKernelGGL(qkv_mfma, dim3(36, 128), dim3(256), 0, stream,
                       xpk_, wpk_, qkv_b, q, k, qpk, kpk, vpk);
    hipLaunchKernelGGL(row_norms, dim3(24576), dim3(256), 0, stream, q, k, qn4, kn4);

    hipLaunchKernelGGL(qr_fact, dim3(96), dim3(1024), 0, stream, q, k, Vpk2, taug);
    hipLaunchKernelGGL(qr_gpart, dim3(96, 4), dim3(256), 0, stream, Vpk2, Gpart);
    hipLaunchKernelGGL(qr_tw2, dim3(96), dim3(256), 0, stream, Vpk2, taug, Gpart, Wg);
    hipLaunchKernelGGL(qr_formq, dim3(96, 16), dim3(256), 0, stream, Vpk2, Wg, qgrh, kgrh);

    hipLaunchKernelGGL(pack_f32, dim3(576), dim3(256), 0, stream, proj_w, ppk, 147456);

    if (full) {
        hipLaunchKernelGGL(sattn_scores, dim3(16, 32, 4), dim3(512), 0, stream,
                           qpk, kpk, qgrh, kgrh, qn4, kn4, conv_w, conv_b,
                           bn_gamma, bn_beta, bn_mean, bn_var,
                           scale, riem_scale, grass_scale, Sbuf, 0);
        hipLaunchKernelGGL(sattn_pv, dim3(64, 12, 4), dim3(256), 0, stream,
                           vpk, Sbuf, attno_pk, 0);
    } else {
        for (int b = 0; b < 4; b++) {
            hipLaunchKernelGGL(sattn_scores, dim3(16, 32, 1), dim3(512), 0, stream,
                               qpk, kpk, qgrh, kgrh, qn4, kn4, conv_w, conv_b,
                               bn_gamma, bn_beta, bn_mean, bn_var,
                               scale, riem_scale, grass_scale, Sbuf, b);
            hipLaunchKernelGGL(sattn_pv, dim3(64, 12, 1), dim3(256), 0, stream,
                               vpk, Sbuf, attno_pk, b);
        }
    }

    hipLaunchKernelGGL(proj_mfma, dim3(12, 128), dim3(256), 0, stream,
                       attno_pk, ppk, proj_b, out);
}